// Round 5
// baseline (277.643 us; speedup 1.0000x reference)
//
#include <hip/hip_runtime.h>
#include <math.h>

#define SEQ  1024
#define IND  256
#define CC   1024
#define NH   8
#define HD   128
#define BH   64      // BATCH*NH

typedef __bf16 bf16x8 __attribute__((ext_vector_type(8)));
typedef __bf16 bf16x4 __attribute__((ext_vector_type(4)));
typedef float  f32x4  __attribute__((ext_vector_type(4)));
typedef unsigned short u16;

static constexpr float RSDK = 0.08838834764831845f;  // 1/sqrt(128)

__device__ __forceinline__ u16 f2bf(float f) {
    unsigned int u = __float_as_uint(f);
    u += 0x7fffu + ((u >> 16) & 1u);   // round-to-nearest-even
    return (u16)(u >> 16);
}

__device__ __forceinline__ unsigned cvt_pk_bf16(float lo, float hi) {
    unsigned r;
    asm("v_cvt_pk_bf16_f32 %0, %1, %2" : "=v"(r) : "v"(lo), "v"(hi));
    return r;
}

// ---------------------------------------------------------------------------
// P0: fused prep. 1D grid 2944, block 256.
//   id <  2048          : x fp32 -> bf16 (4 elems/thread)
//   2048 <= id < 2816   : wq/wk/wv [256][1024] -> bf16 [1024][256] transpose
//   2816 <= id < 2944   : proj_w [1024][128]  -> bf16 [128][1024] transpose
// ---------------------------------------------------------------------------
__global__ __launch_bounds__(256) void prep_kernel(
    const float* __restrict__ x, u16* __restrict__ xb,
    const float* __restrict__ w0, const float* __restrict__ w1, const float* __restrict__ w2,
    u16* __restrict__ o0, u16* __restrict__ o1, u16* __restrict__ o2,
    const float* __restrict__ pw, u16* __restrict__ pT)
{
    __shared__ float tile[32][33];
    const int id = blockIdx.x;

    if (id < 2048) {
        const int i = id * 256 + threadIdx.x;
        float4 v = ((const float4*)x)[i];
        ushort4 o;
        o.x = f2bf(v.x); o.y = f2bf(v.y); o.z = f2bf(v.z); o.w = f2bf(v.w);
        ((ushort4*)xb)[i] = o;
        return;
    }

    const float* in; u16* out; int R, C, c0, r0;
    if (id < 2816) {
        const int rem = id - 2048;
        const int z = rem >> 8;              // 0..2
        const int rem2 = rem & 255;
        in  = (z == 0) ? w0 : (z == 1) ? w1 : w2;
        out = (z == 0) ? o0 : (z == 1) ? o1 : o2;
        R = IND; C = CC;
        c0 = (rem2 & 31) * 32;               // 0..992
        r0 = (rem2 >> 5) * 32;               // 0..224
    } else {
        const int rem = id - 2816;
        in = pw; out = pT;
        R = CC; C = HD;
        c0 = (rem & 3) * 32;                 // 0..96
        r0 = (rem >> 2) * 32;                // 0..992
    }

    const int row = threadIdx.x >> 3, col4 = (threadIdx.x & 7) * 4;
    float4 v = *(const float4*)&in[(size_t)(r0 + row) * C + c0 + col4];
    tile[row][col4 + 0] = v.x; tile[row][col4 + 1] = v.y;
    tile[row][col4 + 2] = v.z; tile[row][col4 + 3] = v.w;
    __syncthreads();
    ushort4 o;
    o.x = f2bf(tile[col4 + 0][row]);
    o.y = f2bf(tile[col4 + 1][row]);
    o.z = f2bf(tile[col4 + 2][row]);
    o.w = f2bf(tile[col4 + 3][row]);
    *(ushort4*)&out[(size_t)(c0 + row) * R + r0 + col4] = o;
}

// ---------------------------------------------------------------------------
// K1: QKV MFMA GEMM (R8/R12-exact). M=8192,N=1024,K=256. grid (64, 8, 3),
// block 256. 128x128 tile, BK=64, padded rows (stride 72 u16).
// mat 0/1 (Q,K): write [bh][n][128]; mat 2 (V): write TRANSPOSED [bh][128][n].
// ---------------------------------------------------------------------------
#define QKV_LDW 72
__global__ __launch_bounds__(256) void qkv_kernel(
    const u16* __restrict__ xb,
    const u16* __restrict__ wT0, const u16* __restrict__ wT1, const u16* __restrict__ wT2,
    const float* __restrict__ b0, const float* __restrict__ b1, const float* __restrict__ b2,
    u16* __restrict__ q_out, u16* __restrict__ k_out, u16* __restrict__ vt_out)
{
    const int mat = blockIdx.z;
    const u16* wT  = (mat == 0) ? wT0 : (mat == 1) ? wT1 : wT2;
    const float* wb = (mat == 0) ? b0 : (mat == 1) ? b1 : b2;
    const float scale = (mat == 0) ? RSDK : 1.0f;

    __shared__ __align__(16) u16 As[128 * QKV_LDW];
    __shared__ __align__(16) u16 Bs[128 * QKV_LDW];

    const int tid = threadIdx.x;
    const int lane = tid & 63, wave = tid >> 6;
    const int ln = lane & 15, quad = lane >> 4;
    const int m0 = blockIdx.x * 128;
    const int n0 = blockIdx.y * 128;
    const int wm = (wave & 1) * 64;
    const int wn = (wave >> 1) * 64;

    f32x4 acc[4][4];
    #pragma unroll
    for (int mb = 0; mb < 4; ++mb)
        #pragma unroll
        for (int nb = 0; nb < 4; ++nb)
            #pragma unroll
            for (int r = 0; r < 4; ++r) acc[mb][nb][r] = 0.0f;

    const int r8 = tid >> 3, pb8 = tid & 7;   // row-within-32, 16B block

    const u16* ag = xb + (size_t)(m0 + r8) * IND + pb8 * 8;
    const u16* bg = wT + (size_t)(n0 + r8) * IND + pb8 * 8;

    bf16x8 pa[4], pbv[4];
    #pragma unroll
    for (int c = 0; c < 4; ++c) {
        pa[c]  = *(const bf16x8*)(ag + (size_t)c * 32 * IND);
        pbv[c] = *(const bf16x8*)(bg + (size_t)c * 32 * IND);
    }

    for (int kt = 0; kt < 4; ++kt) {
        __syncthreads();
        #pragma unroll
        for (int c = 0; c < 4; ++c) {
            *(bf16x8*)(As + (size_t)(c * 32 + r8) * QKV_LDW + pb8 * 8) = pa[c];
            *(bf16x8*)(Bs + (size_t)(c * 32 + r8) * QKV_LDW + pb8 * 8) = pbv[c];
        }
        __syncthreads();
        if (kt < 3) {
            #pragma unroll
            for (int c = 0; c < 4; ++c) {
                pa[c]  = *(const bf16x8*)(ag + (size_t)c * 32 * IND + (kt + 1) * 64);
                pbv[c] = *(const bf16x8*)(bg + (size_t)c * 32 * IND + (kt + 1) * 64);
            }
        }
        #pragma unroll
        for (int ks = 0; ks < 2; ++ks) {
            bf16x8 af[4], bf[4];
            #pragma unroll
            for (int mb = 0; mb < 4; ++mb)
                af[mb] = *(const bf16x8*)(As + (size_t)(wm + mb * 16 + ln) * QKV_LDW
                                             + (ks * 4 + quad) * 8);
            #pragma unroll
            for (int nb = 0; nb < 4; ++nb)
                bf[nb] = *(const bf16x8*)(Bs + (size_t)(wn + nb * 16 + ln) * QKV_LDW
                                             + (ks * 4 + quad) * 8);
            #pragma unroll
            for (int mb = 0; mb < 4; ++mb)
                #pragma unroll
                for (int nb = 0; nb < 4; ++nb)
                    acc[mb][nb] = __builtin_amdgcn_mfma_f32_16x16x32_bf16(
                        af[mb], bf[nb], acc[mb][nb], 0, 0, 0);
        }
    }

    if (mat != 2) {
        u16* outp = (mat == 0) ? q_out : k_out;
        #pragma unroll
        for (int nb = 0; nb < 4; ++nb) {
            const int c = n0 + wn + nb * 16 + ln;
            const float bv = wb[c];
            const int h = c >> 7, d = c & 127;
            #pragma unroll
            for (int mb = 0; mb < 4; ++mb) {
                #pragma unroll
                for (int r = 0; r < 4; ++r) {
                    const int m = m0 + wm + mb * 16 + quad * 4 + r;
                    const int b = m >> 10, tok = m & 1023;
                    outp[((size_t)(b * NH + h) * SEQ + tok) * HD + d] =
                        f2bf((acc[mb][nb][r] + bv) * scale);
                }
            }
        }
    } else {
        // V: fused transpose -> Vt [bh][d][n]; 4 consecutive tokens per store
        #pragma unroll
        for (int nb = 0; nb < 4; ++nb) {
            const int c = n0 + wn + nb * 16 + ln;
            const float bv = wb[c];
            const int h = c >> 7, d = c & 127;
            #pragma unroll
            for (int mb = 0; mb < 4; ++mb) {
                const int m = m0 + wm + mb * 16 + quad * 4;
                const int b = m >> 10, tok0 = m & 1023;
                ushort4 o;
                o.x = f2bf(acc[mb][nb][0] + bv);
                o.y = f2bf(acc[mb][nb][1] + bv);
                o.z = f2bf(acc[mb][nb][2] + bv);
                o.w = f2bf(acc[mb][nb][3] + bv);
                *(ushort4*)&vt_out[((size_t)(b * NH + h) * HD + d) * SEQ + tok0] = o;
            }
        }
    }
}

// ---------------------------------------------------------------------------
// K2: flash attention, MFMA. R19: K-fragments DIRECT from global/L2; K LDS
// tile deleted. Sync structure is R17's proven 2-barrier form (R18's
// single-barrier dbuf RACED: nondeterministic absmax 1.3e-2 / 468 across
// launches — negative result, do not retry without exact HK-style waits).
// grid (64 bh, 16 q-blocks), block 256; wave owns 16 q-rows, KVB=32,
// in-register P (R17 swapped-QK + cvt_pk/permlane transpose kept).
// Rationale: R17 counters showed LDS pipe ~75% busy (20 b128/lane/kt vs
// 165k-cyc wall), MfmaUtil 20%, HBM 12% -> LDS is the limiter. kf address
// K[key][d-chunk] is row-major 16B/lane, identical across all 4 waves of the
// block -> L1 amortizes; worst-case ~1 GB L2 reads (~17 TB/s) vs 34.5
// ceiling. Removes 8 ds_reads + 2 ds_writes + 2 staging loads per lane/kt
// (LDS ops 20 -> 10). kf loads issued at TOP of body; barriers + V-stage
// cover their L2 latency. Bit-exact vs R17 (same values, same order).
// Unnormalized softmax (|s| <~ 10 << 88), p = exp(s), l in regs.
// Vs: [128 d][32 k] stride 40 u16.
// Negative results kept out: XOR swizzle (R3/4), P pair-pack via LDS (R7),
// V-direct+single-barrier (R9), bias-as-C (R13), exp2 fold (R14),
// single-barrier dbuf (R18 race).
// ---------------------------------------------------------------------------
#define KVB    32
#define VS_LDW 40
__global__ __launch_bounds__(256, 4) void attn_kernel(
    const u16* __restrict__ Q, const u16* __restrict__ K,
    const u16* __restrict__ Vt, const float* __restrict__ bias,
    u16* __restrict__ aout)
{
    __shared__ __align__(16) u16 Vs[128 * VS_LDW];        // 10240 B

    const int tid = threadIdx.x;
    const int lane = tid & 63, wave = tid >> 6;
    const int ln = lane & 15, quad = lane >> 4;
    const int bh = blockIdx.x;
    const int q0 = blockIdx.y * 64 + wave * 16;

    bf16x8 qf[4];
    {
        const u16* qp = Q + ((size_t)bh * SEQ + q0 + ln) * HD + quad * 8;
        #pragma unroll
        for (int ks = 0; ks < 4; ++ks) qf[ks] = *(const bf16x8*)(qp + ks * 32);
    }

    f32x4 Oa[8];
    #pragma unroll
    for (int db = 0; db < 8; ++db)
        #pragma unroll
        for (int r = 0; r < 4; ++r) Oa[db][r] = 0.0f;
    float l_loc = 0.0f;   // partial l for query ln (keys of this quad)

    const u16* Kg0 = K  + (size_t)bh * SEQ * HD;
    const u16* Vg0 = Vt + (size_t)bh * HD * SEQ;
    // bias row for THIS lane's query (ln); float4-contiguous in key dim
    const float* brow = bias + (size_t)(q0 + ln) * SEQ + quad * 4;

    // K fragment base: row = key (kt*KVB + nb*16 + ln), 16B chunk = d
    // ((ks*4+quad)*8). Wave-index-independent -> L1-shared across waves.
    const u16* kfg = Kg0 + (size_t)ln * HD + quad * 8;

    // V staging indices (R17-exact)
    const int r4 = tid >> 2, pb4 = tid & 3;
    const u16* vg = Vg0 + (size_t)r4 * SEQ + pb4 * 8;    // + c*64*SEQ + kt*KVB

    bf16x8 vp[2];
    #pragma unroll
    for (int c = 0; c < 2; ++c)
        vp[c] = *(const bf16x8*)(vg + (size_t)c * 64 * SEQ);

    // bias prefetch for kt=0: [nb] = keys nb*16 + quad*4 + {0..3}
    float4 bpre[2];
    #pragma unroll
    for (int nb = 0; nb < 2; ++nb)
        bpre[nb] = *(const float4*)(brow + nb * 16);

    for (int kt = 0; kt < 32; ++kt) {
        // ---- issue this tile's K-fragment loads early (L2-latency cover
        //      = barrier + V-stage + barrier + vp issue) ----
        bf16x8 kf[2][4];
        #pragma unroll
        for (int nb = 0; nb < 2; ++nb)
            #pragma unroll
            for (int ks = 0; ks < 4; ++ks)
                kf[nb][ks] = *(const bf16x8*)(kfg
                    + (size_t)(kt * KVB + nb * 16) * HD + ks * 32);

        __syncthreads();
        #pragma unroll
        for (int c = 0; c < 2; ++c)
            *(bf16x8*)(Vs + (size_t)(c * 64 + r4) * VS_LDW + pb4 * 8) = vp[c];
        __syncthreads();

        // prefetch next V tile (off critical path)
        if (kt < 31) {
            #pragma unroll
            for (int c = 0; c < 2; ++c)
                vp[c] = *(const bf16x8*)(vg + (size_t)c * 64 * SEQ + (kt + 1) * KVB);
        }

        // ---- S^T = K Q^T (swapped operands); p = exp(s + bias), in-reg ----
        float p8[2][4];
        #pragma unroll
        for (int nb = 0; nb < 2; ++nb) {
            f32x4 s;
            #pragma unroll
            for (int r = 0; r < 4; ++r) s[r] = 0.0f;
            #pragma unroll
            for (int ks = 0; ks < 4; ++ks)
                s = __builtin_amdgcn_mfma_f32_16x16x32_bf16(kf[nb][ks], qf[ks], s, 0, 0, 0);
            #pragma unroll
            for (int r = 0; r < 4; ++r) {
                const float p = __expf(s[r] + bpre[nb][r]);
                l_loc += p;
                p8[nb][r] = p;
            }
        }

        // bias for kt+1 (after last use of bpre; hidden under PV)
        if (kt < 31) {
            #pragma unroll
            for (int nb = 0; nb < 2; ++nb)
                bpre[nb] = *(const float4*)(brow + (kt + 1) * KVB + nb * 16);
        }

        // ---- P -> A fragment: pure-register 4-quad transpose ----
        unsigned x0 = cvt_pk_bf16(p8[0][0], p8[0][1]);   // keys 4q+0,4q+1
        unsigned x1 = cvt_pk_bf16(p8[0][2], p8[0][3]);   // keys 4q+2,4q+3
        unsigned y0 = cvt_pk_bf16(p8[1][0], p8[1][1]);   // keys 16+4q+0,+1
        unsigned y1 = cvt_pk_bf16(p8[1][2], p8[1][3]);   // keys 16+4q+2,+3
        asm("v_permlane32_swap_b32 %0, %1" : "+v"(x0), "+v"(y0));
        asm("v_permlane32_swap_b32 %0, %1" : "+v"(x1), "+v"(y1));
        asm("v_permlane16_swap_b32 %0, %1" : "+v"(x0), "+v"(y0));
        asm("v_permlane16_swap_b32 %0, %1" : "+v"(x1), "+v"(y1));
        union { unsigned u[4]; bf16x8 v; } afu;
        afu.u[0] = x0; afu.u[1] = x1; afu.u[2] = y0; afu.u[3] = y1;
        const bf16x8 af = afu.v;   // P[q=ln][keys 8*quad .. 8*quad+7]

        // ---- O += P V (8 independent MFMAs) ----
        #pragma unroll
        for (int db = 0; db < 8; ++db) {
            bf16x8 vf = *(const bf16x8*)(Vs + (size_t)(db * 16 + ln) * VS_LDW + quad * 8);
            Oa[db] = __builtin_amdgcn_mfma_f32_16x16x32_bf16(af, vf, Oa[db], 0, 0, 0);
        }
    }

    // ---- l reduce across quads; lane (ln,*) -> l_tot[query=ln] ----
    float ltot = l_loc;
    ltot += __shfl_xor(ltot, 16);
    ltot += __shfl_xor(ltot, 32);

    // ---- epilogue: Oa[db][r] is O[q=quad*4+r][d=db*16+ln] ----
    const int b = bh >> 3, h = bh & 7;
    #pragma unroll
    for (int r = 0; r < 4; ++r) {
        const float inv = 1.0f / __shfl(ltot, quad * 4 + r);
        const int tok = q0 + quad * 4 + r;
        u16* op = aout + ((size_t)(b * SEQ + tok)) * CC + h * HD + ln;
        #pragma unroll
        for (int db = 0; db < 8; ++db) op[db * 16] = f2bf(Oa[db][r] * inv);
    }
}

// ---------------------------------------------------------------------------
// K3: output projection, 4-way K-split (R12-exact). M=8192, N=128, K=1024.
// grid 512, block 256 (4 waves). Wave kh owns K-quarter of the SAME 16 rows;
// waves 1-3 write fp32 partials to LDS (stride 132), wave 0 sums + bias.
// (2048 waves = 8 waves/CU; this was the R12 win, total 229 -> 197.)
// ---------------------------------------------------------------------------
__global__ __launch_bounds__(256) void proj_kernel(
    const u16* __restrict__ A, const u16* __restrict__ pT,
    const float* __restrict__ pb, float* __restrict__ out)
{
    __shared__ float Rs[3][16 * 132];
    const int tid = threadIdx.x;
    const int lane = tid & 63, kh = tid >> 6;
    const int ln = lane & 15, quad = lane >> 4;
    const int m0 = blockIdx.x * 16;

    f32x4 acc[8];
    #pragma unroll
    for (int nb = 0; nb < 8; ++nb)
        #pragma unroll
        for (int r = 0; r < 4; ++r) acc[nb][r] = 0.0f;

    const u16* ap = A  + (size_t)(m0 + ln) * CC + kh * 256 + quad * 8;
    const u16* bp = pT + (size_t)ln * CC + kh * 256 + quad * 8;

    #pragma unroll
    for (int kt = 0; kt < 8; ++kt) {
        bf16x8 af = *(const bf16x8*)(ap + kt * 32);
        #pragma unroll
        for (int nb = 0; nb < 8; ++nb) {
            bf16x8 bf = *(const bf16x8*)(bp + (size_t)nb * 16 * CC + kt * 32);
            acc[nb] = __builtin_amdgcn_mfma_f32_16x16x32_bf16(af, bf, acc[nb], 0, 0, 0);
        }
    }

    if (kh > 0) {
        #pragma unroll
        for (int nb = 0; nb < 8; ++nb)
            #pragma unroll
            for (int r = 0; r < 4; ++r)
                Rs[kh - 1][(quad * 4 + r) * 132 + nb * 16 + ln] = acc[nb][r];
    }
    __syncthreads();
    if (kh == 0) {
        #pragma unroll
        for (int nb = 0; nb < 8; ++nb) {
            const int c = nb * 16 + ln;
            const float bv = pb[c];
            #pragma unroll
            for (int r = 0; r < 4; ++r) {
                const int ri = (quad * 4 + r) * 132 + c;
                out[(size_t)(m0 + quad * 4 + r) * HD + c] =
                    acc[nb][r] + Rs[0][ri] + Rs[1][ri] + Rs[2][ri] + bv;
            }
        }
    }
}

// ---------------------------------------------------------------------------
extern "C" void kernel_launch(void* const* d_in, const int* in_sizes, int n_in,
                              void* d_out, int out_size, void* d_ws, size_t ws_size,
                              hipStream_t stream)
{
    const float* x    = (const float*)d_in[0];
    const float* bias = (const float*)d_in[1];
    const float* wq   = (const float*)d_in[2];
    const float* wqb  = (const float*)d_in[3];
    const float* wk   = (const float*)d_in[4];
    const float* wkb  = (const float*)d_in[5];
    const float* wv   = (const float*)d_in[6];
    const float* wvb  = (const float*)d_in[7];
    const float* pw   = (const float*)d_in[8];
    const float* pb   = (const float*)d_in[9];
    float* out = (float*)d_out;

    u16* ws = (u16*)d_ws;
    size_t off = 0;
    u16* xb  = ws + off; off += (size_t)8192 * IND;     // 4 MB
    u16* wqT = ws + off; off += (size_t)CC * IND;       // 512 KB
    u16* wkT = ws + off; off += (size_t)CC * IND;
    u16* wvT = ws + off; off += (size_t)CC * IND;
    u16* pT  = ws + off; off += (size_t)HD * CC;        // 256 KB
    u16* Qw  = ws + off; off += (size_t)BH * SEQ * HD;  // 16 MB
    u16* Kw  = ws + off; off += (size_t)BH * SEQ * HD;
    u16* Vtw = ws + off; off += (size_t)BH * HD * SEQ;
    u16* Aw  = ws + off; off += (size_t)8192 * CC;      // 16 MB

    prep_kernel<<<2944, 256, 0, stream>>>(x, xb, wq, wk, wv, wqT, wkT, wvT, pw, pT);
    qkv_kernel<<<dim3(64, 8, 3), 256, 0, stream>>>(
        xb, wqT, wkT, wvT, wqb, wkb, wvb, Qw, Kw, Vtw);
    attn_kernel<<<dim3(64, 16), 256, 0, stream>>>(Qw, Kw, Vtw, bias, Aw);
    proj_kernel<<<512, 256, 0, stream>>>(Aw, pT, pb, out);
}

// Round 6
// 172.083 us; speedup vs baseline: 1.6134x; 1.6134x over previous
//
#include <hip/hip_runtime.h>
#include <math.h>

#define SEQ  1024
#define IND  256
#define CC   1024
#define NH   8
#define HD   128
#define BH   64      // BATCH*NH

typedef __bf16 bf16x8 __attribute__((ext_vector_type(8)));
typedef __bf16 bf16x4 __attribute__((ext_vector_type(4)));
typedef float  f32x4  __attribute__((ext_vector_type(4)));
typedef unsigned short u16;

static constexpr float RSDK = 0.08838834764831845f;  // 1/sqrt(128)

__device__ __forceinline__ u16 f2bf(float f) {
    unsigned int u = __float_as_uint(f);
    u += 0x7fffu + ((u >> 16) & 1u);   // round-to-nearest-even
    return (u16)(u >> 16);
}

__device__ __forceinline__ unsigned cvt_pk_bf16(float lo, float hi) {
    unsigned r;
    asm("v_cvt_pk_bf16_f32 %0, %1, %2" : "=v"(r) : "v"(lo), "v"(hi));
    return r;
}

// ---------------------------------------------------------------------------
// P0: fused prep. 1D grid 2944, block 256.
//   id <  2048          : x fp32 -> bf16 (4 elems/thread)
//   2048 <= id < 2816   : wq/wk/wv [256][1024] -> bf16 [1024][256] transpose
//   2816 <= id < 2944   : proj_w [1024][128]  -> bf16 [128][1024] transpose
// ---------------------------------------------------------------------------
__global__ __launch_bounds__(256) void prep_kernel(
    const float* __restrict__ x, u16* __restrict__ xb,
    const float* __restrict__ w0, const float* __restrict__ w1, const float* __restrict__ w2,
    u16* __restrict__ o0, u16* __restrict__ o1, u16* __restrict__ o2,
    const float* __restrict__ pw, u16* __restrict__ pT)
{
    __shared__ float tile[32][33];
    const int id = blockIdx.x;

    if (id < 2048) {
        const int i = id * 256 + threadIdx.x;
        float4 v = ((const float4*)x)[i];
        ushort4 o;
        o.x = f2bf(v.x); o.y = f2bf(v.y); o.z = f2bf(v.z); o.w = f2bf(v.w);
        ((ushort4*)xb)[i] = o;
        return;
    }

    const float* in; u16* out; int R, C, c0, r0;
    if (id < 2816) {
        const int rem = id - 2048;
        const int z = rem >> 8;              // 0..2
        const int rem2 = rem & 255;
        in  = (z == 0) ? w0 : (z == 1) ? w1 : w2;
        out = (z == 0) ? o0 : (z == 1) ? o1 : o2;
        R = IND; C = CC;
        c0 = (rem2 & 31) * 32;               // 0..992
        r0 = (rem2 >> 5) * 32;               // 0..224
    } else {
        const int rem = id - 2816;
        in = pw; out = pT;
        R = CC; C = HD;
        c0 = (rem & 3) * 32;                 // 0..96
        r0 = (rem >> 2) * 32;                // 0..992
    }

    const int row = threadIdx.x >> 3, col4 = (threadIdx.x & 7) * 4;
    float4 v = *(const float4*)&in[(size_t)(r0 + row) * C + c0 + col4];
    tile[row][col4 + 0] = v.x; tile[row][col4 + 1] = v.y;
    tile[row][col4 + 2] = v.z; tile[row][col4 + 3] = v.w;
    __syncthreads();
    ushort4 o;
    o.x = f2bf(tile[col4 + 0][row]);
    o.y = f2bf(tile[col4 + 1][row]);
    o.z = f2bf(tile[col4 + 2][row]);
    o.w = f2bf(tile[col4 + 3][row]);
    *(ushort4*)&out[(size_t)(c0 + row) * R + r0 + col4] = o;
}

// ---------------------------------------------------------------------------
// K1: QKV MFMA GEMM (R8/R12-exact). M=8192,N=1024,K=256. grid (64, 8, 3),
// block 256. 128x128 tile, BK=64, padded rows (stride 72 u16).
// mat 0/1 (Q,K): write [bh][n][128]; mat 2 (V): write TRANSPOSED [bh][128][n].
// ---------------------------------------------------------------------------
#define QKV_LDW 72
__global__ __launch_bounds__(256) void qkv_kernel(
    const u16* __restrict__ xb,
    const u16* __restrict__ wT0, const u16* __restrict__ wT1, const u16* __restrict__ wT2,
    const float* __restrict__ b0, const float* __restrict__ b1, const float* __restrict__ b2,
    u16* __restrict__ q_out, u16* __restrict__ k_out, u16* __restrict__ vt_out)
{
    const int mat = blockIdx.z;
    const u16* wT  = (mat == 0) ? wT0 : (mat == 1) ? wT1 : wT2;
    const float* wb = (mat == 0) ? b0 : (mat == 1) ? b1 : b2;
    const float scale = (mat == 0) ? RSDK : 1.0f;

    __shared__ __align__(16) u16 As[128 * QKV_LDW];
    __shared__ __align__(16) u16 Bs[128 * QKV_LDW];

    const int tid = threadIdx.x;
    const int lane = tid & 63, wave = tid >> 6;
    const int ln = lane & 15, quad = lane >> 4;
    const int m0 = blockIdx.x * 128;
    const int n0 = blockIdx.y * 128;
    const int wm = (wave & 1) * 64;
    const int wn = (wave >> 1) * 64;

    f32x4 acc[4][4];
    #pragma unroll
    for (int mb = 0; mb < 4; ++mb)
        #pragma unroll
        for (int nb = 0; nb < 4; ++nb)
            #pragma unroll
            for (int r = 0; r < 4; ++r) acc[mb][nb][r] = 0.0f;

    const int r8 = tid >> 3, pb8 = tid & 7;   // row-within-32, 16B block

    const u16* ag = xb + (size_t)(m0 + r8) * IND + pb8 * 8;
    const u16* bg = wT + (size_t)(n0 + r8) * IND + pb8 * 8;

    bf16x8 pa[4], pbv[4];
    #pragma unroll
    for (int c = 0; c < 4; ++c) {
        pa[c]  = *(const bf16x8*)(ag + (size_t)c * 32 * IND);
        pbv[c] = *(const bf16x8*)(bg + (size_t)c * 32 * IND);
    }

    for (int kt = 0; kt < 4; ++kt) {
        __syncthreads();
        #pragma unroll
        for (int c = 0; c < 4; ++c) {
            *(bf16x8*)(As + (size_t)(c * 32 + r8) * QKV_LDW + pb8 * 8) = pa[c];
            *(bf16x8*)(Bs + (size_t)(c * 32 + r8) * QKV_LDW + pb8 * 8) = pbv[c];
        }
        __syncthreads();
        if (kt < 3) {
            #pragma unroll
            for (int c = 0; c < 4; ++c) {
                pa[c]  = *(const bf16x8*)(ag + (size_t)c * 32 * IND + (kt + 1) * 64);
                pbv[c] = *(const bf16x8*)(bg + (size_t)c * 32 * IND + (kt + 1) * 64);
            }
        }
        #pragma unroll
        for (int ks = 0; ks < 2; ++ks) {
            bf16x8 af[4], bf[4];
            #pragma unroll
            for (int mb = 0; mb < 4; ++mb)
                af[mb] = *(const bf16x8*)(As + (size_t)(wm + mb * 16 + ln) * QKV_LDW
                                             + (ks * 4 + quad) * 8);
            #pragma unroll
            for (int nb = 0; nb < 4; ++nb)
                bf[nb] = *(const bf16x8*)(Bs + (size_t)(wn + nb * 16 + ln) * QKV_LDW
                                             + (ks * 4 + quad) * 8);
            #pragma unroll
            for (int mb = 0; mb < 4; ++mb)
                #pragma unroll
                for (int nb = 0; nb < 4; ++nb)
                    acc[mb][nb] = __builtin_amdgcn_mfma_f32_16x16x32_bf16(
                        af[mb], bf[nb], acc[mb][nb], 0, 0, 0);
        }
    }

    if (mat != 2) {
        u16* outp = (mat == 0) ? q_out : k_out;
        #pragma unroll
        for (int nb = 0; nb < 4; ++nb) {
            const int c = n0 + wn + nb * 16 + ln;
            const float bv = wb[c];
            const int h = c >> 7, d = c & 127;
            #pragma unroll
            for (int mb = 0; mb < 4; ++mb) {
                #pragma unroll
                for (int r = 0; r < 4; ++r) {
                    const int m = m0 + wm + mb * 16 + quad * 4 + r;
                    const int b = m >> 10, tok = m & 1023;
                    outp[((size_t)(b * NH + h) * SEQ + tok) * HD + d] =
                        f2bf((acc[mb][nb][r] + bv) * scale);
                }
            }
        }
    } else {
        // V: fused transpose -> Vt [bh][d][n]; 4 consecutive tokens per store
        #pragma unroll
        for (int nb = 0; nb < 4; ++nb) {
            const int c = n0 + wn + nb * 16 + ln;
            const float bv = wb[c];
            const int h = c >> 7, d = c & 127;
            #pragma unroll
            for (int mb = 0; mb < 4; ++mb) {
                const int m = m0 + wm + mb * 16 + quad * 4;
                const int b = m >> 10, tok0 = m & 1023;
                ushort4 o;
                o.x = f2bf(acc[mb][nb][0] + bv);
                o.y = f2bf(acc[mb][nb][1] + bv);
                o.z = f2bf(acc[mb][nb][2] + bv);
                o.w = f2bf(acc[mb][nb][3] + bv);
                *(ushort4*)&vt_out[((size_t)(b * NH + h) * HD + d) * SEQ + tok0] = o;
            }
        }
    }
}

// ---------------------------------------------------------------------------
// K2: flash attention, MFMA. R20: wave owns 32 q-rows (2 q-tiles) sharing
// one set of K/V fragment reads. grid (64 bh, 8 q-blocks), block 256,
// launch_bounds(256,2). R17 2-barrier sync + in-register P kept.
// Post-mortems driving this: R18 single-barrier dbuf RACED (revert);
// R19 K-direct-from-global REGRESSED 69->163 us (fragment reads from global
// are uncoalesced: 16 lanes stride 256B -> transaction explosion; staged
// LDS is mandatory for K AND V). R17 accounting: LDS pipe ~75% busy
// (10.2k b128 wave-instrs/CU x 12cy = 123k of 165k wall), MFMA 20%,
// VALU 26%. Fragment reads (8 kf + 8 vf per lane/kt) are q-tile-
// independent -> a 2-q-tile wave halves LDS instrs per unit work (61k/CU).
// Occupancy drops to 2 blocks/CU (2 waves/SIMD) but the wave now carries
// two independent q-tile chains for ILP, and the loaded pipe is cut 2x.
// Bit-exact per row: same key order, same per-row ops as R17.
// Unnormalized softmax (|s| <~ 10 << 88), p = exp(s), l in regs.
// Ks: [32 k][128 d] stride 136 u16; Vs: [128 d][32 k] stride 40 u16.
// Negative results kept out: XOR swizzle (R3/4), P pair-pack via LDS (R7),
// V-direct (R9), bias-as-C (R13), exp2 fold (R14), single-barrier dbuf
// (R18 race), K-direct-global (R19). Fallback if this regresses: R17+setprio.
// ---------------------------------------------------------------------------
#define KVB    32
#define KS_LDW 136
#define VS_LDW 40
__global__ __launch_bounds__(256, 2) void attn_kernel(
    const u16* __restrict__ Q, const u16* __restrict__ K,
    const u16* __restrict__ Vt, const float* __restrict__ bias,
    u16* __restrict__ aout)
{
    __shared__ __align__(16) u16 Ks[KVB * KS_LDW];        // 8704 B
    __shared__ __align__(16) u16 Vs[128 * VS_LDW];        // 10240 B

    const int tid = threadIdx.x;
    const int lane = tid & 63, wave = tid >> 6;
    const int ln = lane & 15, quad = lane >> 4;
    const int bh = blockIdx.x;
    const int q0 = blockIdx.y * 128 + wave * 32;

    bf16x8 qf[2][4];
    #pragma unroll
    for (int mb = 0; mb < 2; ++mb) {
        const u16* qp = Q + ((size_t)bh * SEQ + q0 + mb * 16 + ln) * HD + quad * 8;
        #pragma unroll
        for (int ks = 0; ks < 4; ++ks) qf[mb][ks] = *(const bf16x8*)(qp + ks * 32);
    }

    f32x4 Oa[2][8];
    #pragma unroll
    for (int mb = 0; mb < 2; ++mb)
        #pragma unroll
        for (int db = 0; db < 8; ++db)
            #pragma unroll
            for (int r = 0; r < 4; ++r) Oa[mb][db][r] = 0.0f;
    float l_loc[2] = {0.0f, 0.0f};   // partial l for query ln, per q-tile

    const u16* Kg0 = K  + (size_t)bh * SEQ * HD;
    const u16* Vg0 = Vt + (size_t)bh * HD * SEQ;
    // bias rows for THIS lane's queries (ln per tile); float4 in key dim
    const float* brow0 = bias + (size_t)(q0 + ln) * SEQ + quad * 4;
    const float* brow1 = brow0 + (size_t)16 * SEQ;

    // staging indices (R17-exact)
    const int r16 = tid >> 4, pb16 = tid & 15;   // K: 16 rows/pass
    const int r4  = tid >> 2, pb4  = tid & 3;    // V: 64 rows/pass

    const u16* kg = Kg0 + (size_t)r16 * HD + pb16 * 8;   // + kt*KVB*HD + c*16*HD
    const u16* vg = Vg0 + (size_t)r4 * SEQ + pb4 * 8;    // + c*64*SEQ + kt*KVB

    bf16x8 kp[2], vp[2];
    #pragma unroll
    for (int c = 0; c < 2; ++c) {
        kp[c] = *(const bf16x8*)(kg + (size_t)c * 16 * HD);
        vp[c] = *(const bf16x8*)(vg + (size_t)c * 64 * SEQ);
    }

    // bias prefetch for kt=0: [mb][nb] = keys nb*16 + quad*4 + {0..3}
    float4 bpre[2][2];
    #pragma unroll
    for (int mb = 0; mb < 2; ++mb)
        #pragma unroll
        for (int nb = 0; nb < 2; ++nb)
            bpre[mb][nb] = *(const float4*)((mb ? brow1 : brow0) + nb * 16);

    for (int kt = 0; kt < 32; ++kt) {
        __syncthreads();
        #pragma unroll
        for (int c = 0; c < 2; ++c) {
            *(bf16x8*)(Ks + (size_t)(c * 16 + r16) * KS_LDW + pb16 * 8) = kp[c];
            *(bf16x8*)(Vs + (size_t)(c * 64 + r4) * VS_LDW + pb4 * 8)   = vp[c];
        }
        __syncthreads();

        // prefetch next K/V tile (off critical path)
        if (kt < 31) {
            #pragma unroll
            for (int c = 0; c < 2; ++c) {
                kp[c] = *(const bf16x8*)(kg + (size_t)(kt + 1) * KVB * HD + (size_t)c * 16 * HD);
                vp[c] = *(const bf16x8*)(vg + (size_t)c * 64 * SEQ + (kt + 1) * KVB);
            }
        }

        // ---- S^T = K Q^T (swapped); kf shared by both q-tiles ----
        float p8[2][2][4];
        #pragma unroll
        for (int nb = 0; nb < 2; ++nb) {
            const u16* kr = Ks + (size_t)(nb * 16 + ln) * KS_LDW;
            bf16x8 kf[4];
            #pragma unroll
            for (int ks = 0; ks < 4; ++ks)
                kf[ks] = *(const bf16x8*)(kr + (ks * 4 + quad) * 8);
            #pragma unroll
            for (int mb = 0; mb < 2; ++mb) {
                f32x4 s;
                #pragma unroll
                for (int r = 0; r < 4; ++r) s[r] = 0.0f;
                #pragma unroll
                for (int ks = 0; ks < 4; ++ks)
                    s = __builtin_amdgcn_mfma_f32_16x16x32_bf16(kf[ks], qf[mb][ks], s, 0, 0, 0);
                #pragma unroll
                for (int r = 0; r < 4; ++r) {
                    const float p = __expf(s[r] + bpre[mb][nb][r]);
                    l_loc[mb] += p;
                    p8[mb][nb][r] = p;
                }
            }
        }

        // bias for kt+1 (after last use of bpre; hidden under PV)
        if (kt < 31) {
            #pragma unroll
            for (int mb = 0; mb < 2; ++mb)
                #pragma unroll
                for (int nb = 0; nb < 2; ++nb)
                    bpre[mb][nb] = *(const float4*)((mb ? brow1 : brow0)
                                                    + (kt + 1) * KVB + nb * 16);
        }

        // ---- P -> A fragments: pure-register 4-quad transpose, per tile ----
        bf16x8 af[2];
        #pragma unroll
        for (int mb = 0; mb < 2; ++mb) {
            unsigned x0 = cvt_pk_bf16(p8[mb][0][0], p8[mb][0][1]);
            unsigned x1 = cvt_pk_bf16(p8[mb][0][2], p8[mb][0][3]);
            unsigned y0 = cvt_pk_bf16(p8[mb][1][0], p8[mb][1][1]);
            unsigned y1 = cvt_pk_bf16(p8[mb][1][2], p8[mb][1][3]);
            asm("v_permlane32_swap_b32 %0, %1" : "+v"(x0), "+v"(y0));
            asm("v_permlane32_swap_b32 %0, %1" : "+v"(x1), "+v"(y1));
            asm("v_permlane16_swap_b32 %0, %1" : "+v"(x0), "+v"(y0));
            asm("v_permlane16_swap_b32 %0, %1" : "+v"(x1), "+v"(y1));
            union { unsigned u[4]; bf16x8 v; } afu;
            afu.u[0] = x0; afu.u[1] = x1; afu.u[2] = y0; afu.u[3] = y1;
            af[mb] = afu.v;   // P[q=ln][keys 8*quad .. 8*quad+7]
        }

        // ---- O += P V; vf shared by both q-tiles ----
        #pragma unroll
        for (int db = 0; db < 8; ++db) {
            bf16x8 vf = *(const bf16x8*)(Vs + (size_t)(db * 16 + ln) * VS_LDW + quad * 8);
            #pragma unroll
            for (int mb = 0; mb < 2; ++mb)
                Oa[mb][db] = __builtin_amdgcn_mfma_f32_16x16x32_bf16(
                    af[mb], vf, Oa[mb][db], 0, 0, 0);
        }
    }

    // ---- l reduce across quads + epilogue, per q-tile ----
    const int b = bh >> 3, h = bh & 7;
    #pragma unroll
    for (int mb = 0; mb < 2; ++mb) {
        float ltot = l_loc[mb];
        ltot += __shfl_xor(ltot, 16);
        ltot += __shfl_xor(ltot, 32);
        #pragma unroll
        for (int r = 0; r < 4; ++r) {
            const float inv = 1.0f / __shfl(ltot, quad * 4 + r);
            const int tok = q0 + mb * 16 + quad * 4 + r;
            u16* op = aout + ((size_t)(b * SEQ + tok)) * CC + h * HD + ln;
            #pragma unroll
            for (int db = 0; db < 8; ++db) op[db * 16] = f2bf(Oa[mb][db][r] * inv);
        }
    }
}

// ---------------------------------------------------------------------------
// K3: output projection, 4-way K-split (R12-exact). M=8192, N=128, K=1024.
// grid 512, block 256 (4 waves). Wave kh owns K-quarter of the SAME 16 rows;
// waves 1-3 write fp32 partials to LDS (stride 132), wave 0 sums + bias.
// (2048 waves = 8 waves/CU; this was the R12 win, total 229 -> 197.)
// ---------------------------------------------------------------------------
__global__ __launch_bounds__(256) void proj_kernel(
    const u16* __restrict__ A, const u16* __restrict__ pT,
    const float* __restrict__ pb, float* __restrict__ out)
{
    __shared__ float Rs[3][16 * 132];
    const int tid = threadIdx.x;
    const int lane = tid & 63, kh = tid >> 6;
    const int ln = lane & 15, quad = lane >> 4;
    const int m0 = blockIdx.x * 16;

    f32x4 acc[8];
    #pragma unroll
    for (int nb = 0; nb < 8; ++nb)
        #pragma unroll
        for (int r = 0; r < 4; ++r) acc[nb][r] = 0.0f;

    const u16* ap = A  + (size_t)(m0 + ln) * CC + kh * 256 + quad * 8;
    const u16* bp = pT + (size_t)ln * CC + kh * 256 + quad * 8;

    #pragma unroll
    for (int kt = 0; kt < 8; ++kt) {
        bf16x8 af = *(const bf16x8*)(ap + kt * 32);
        #pragma unroll
        for (int nb = 0; nb < 8; ++nb) {
            bf16x8 bf = *(const bf16x8*)(bp + (size_t)nb * 16 * CC + kt * 32);
            acc[nb] = __builtin_amdgcn_mfma_f32_16x16x32_bf16(af, bf, acc[nb], 0, 0, 0);
        }
    }

    if (kh > 0) {
        #pragma unroll
        for (int nb = 0; nb < 8; ++nb)
            #pragma unroll
            for (int r = 0; r < 4; ++r)
                Rs[kh - 1][(quad * 4 + r) * 132 + nb * 16 + ln] = acc[nb][r];
    }
    __syncthreads();
    if (kh == 0) {
        #pragma unroll
        for (int nb = 0; nb < 8; ++nb) {
            const int c = nb * 16 + ln;
            const float bv = pb[c];
            #pragma unroll
            for (int r = 0; r < 4; ++r) {
                const int ri = (quad * 4 + r) * 132 + c;
                out[(size_t)(m0 + quad * 4 + r) * HD + c] =
                    acc[nb][r] + Rs[0][ri] + Rs[1][ri] + Rs[2][ri] + bv;
            }
        }
    }
}

// ---------------------------------------------------------------------------
extern "C" void kernel_launch(void* const* d_in, const int* in_sizes, int n_in,
                              void* d_out, int out_size, void* d_ws, size_t ws_size,
                              hipStream_t stream)
{
    const float* x    = (const float*)d_in[0];
    const float* bias = (const float*)d_in[1];
    const float* wq   = (const float*)d_in[2];
    const float* wqb  = (const float*)d_in[3];
    const float* wk   = (const float*)d_in[4];
    const float* wkb  = (const float*)d_in[5];
    const float* wv   = (const float*)d_in[6];
    const float* wvb  = (const float*)d_in[7];
    const float* pw   = (const float*)d_in[8];
    const float* pb   = (const float*)d_in[9];
    float* out = (float*)d_out;

    u16* ws = (u16*)d_ws;
    size_t off = 0;
    u16* xb  = ws + off; off += (size_t)8192 * IND;     // 4 MB
    u16* wqT = ws + off; off += (size_t)CC * IND;       // 512 KB
    u16* wkT = ws + off; off += (size_t)CC * IND;
    u16* wvT = ws + off; off += (size_t)CC * IND;
    u16* pT  = ws + off; off += (size_t)HD * CC;        // 256 KB
    u16* Qw  = ws + off; off += (size_t)BH * SEQ * HD;  // 16 MB
    u16* Kw  = ws + off; off += (size_t)BH * SEQ * HD;
    u16* Vtw = ws + off; off += (size_t)BH * HD * SEQ;
    u16* Aw  = ws + off; off += (size_t)8192 * CC;      // 16 MB

    prep_kernel<<<2944, 256, 0, stream>>>(x, xb, wq, wk, wv, wqT, wkT, wvT, pw, pT);
    qkv_kernel<<<dim3(64, 8, 3), 256, 0, stream>>>(
        xb, wqT, wkT, wvT, wqb, wkb, wvb, Qw, Kw, Vtw);
    attn_kernel<<<dim3(64, 8), 256, 0, stream>>>(Qw, Kw, Vtw, bias, Aw);
    proj_kernel<<<512, 256, 0, stream>>>(Aw, pT, pb, out);
}